// Round 1
// baseline (530.205 us; speedup 1.0000x reference)
//
#include <hip/hip_runtime.h>
#include <hip/hip_bf16.h>

#define BQ 4
#define LQ 4096
#define DM 512
#define DK 64
#define NROWS (BQ * DK)        // 256
#define TOPK 16

// ---------------------------------------------------------------------------
// Kernel 1: projection  pT[b][j][i] = sum_k x[b][i][k]*Wq[k][j] + bq[j]
// grid (512, 1, 3), block 256.  Each block: 32 rows x 64 cols.
// ---------------------------------------------------------------------------
__global__ void proj_kernel(const float* __restrict__ q_in,
                            const float* __restrict__ k_in,
                            const float* __restrict__ v_in,
                            const float* __restrict__ Wq,
                            const float* __restrict__ bq,
                            float* __restrict__ ws) {
  const float* x = blockIdx.z == 0 ? q_in : (blockIdx.z == 1 ? k_in : v_in);
  float* outp = ws + (size_t)blockIdx.z * (size_t)(BQ * DK * LQ);

  __shared__ __align__(16) float xs[32][128];   // 16 KB
  __shared__ __align__(16) float wl[64][132];   // 33.8 KB (padded stride)
  __shared__ float tr[64][33];                  // 8.4 KB transpose staging

  const int tid = threadIdx.x;
  const int j = tid & 63;          // output column
  const int rg = tid >> 6;         // row group 0..3 (8 rows each)
  const int R0 = blockIdx.x * 32;  // flattened row base (b*L + i)

  float acc[8];
#pragma unroll
  for (int r = 0; r < 8; ++r) acc[r] = 0.f;

  for (int kc = 0; kc < DM; kc += 128) {
    // stage x tile [32][128]
#pragma unroll
    for (int v = 0; v < 4; ++v) {
      int f = v * 1024 + tid * 4;
      int row = f >> 7, col = f & 127;
      float4 xv = *reinterpret_cast<const float4*>(
          &x[(size_t)(R0 + row) * DM + kc + col]);
      *reinterpret_cast<float4*>(&xs[row][col]) = xv;
    }
    // stage W transposed: wl[j][k]
#pragma unroll
    for (int v = 0; v < 32; ++v) {
      int f = v * 256 + tid;
      int kk = f >> 6, jj = f & 63;
      wl[jj][kk] = Wq[(size_t)(kc + kk) * DK + jj];
    }
    __syncthreads();
#pragma unroll
    for (int k4 = 0; k4 < 128; k4 += 4) {
      float4 wv = *reinterpret_cast<const float4*>(&wl[j][k4]);
#pragma unroll
      for (int rr = 0; rr < 8; ++rr) {
        float4 xv = *reinterpret_cast<const float4*>(&xs[rg * 8 + rr][k4]);
        acc[rr] += xv.x * wv.x + xv.y * wv.y + xv.z * wv.z + xv.w * wv.w;
      }
    }
    __syncthreads();
  }

  float bias = bq[j];
#pragma unroll
  for (int rr = 0; rr < 8; ++rr) tr[j][rg * 8 + rr] = acc[rr] + bias;
  __syncthreads();

  const int b = R0 >> 12;
  const int i0 = R0 & (LQ - 1);
#pragma unroll
  for (int v = 0; v < 8; ++v) {
    int f = v * 256 + tid;         // 0..2047 : jj = f>>5, ii = f&31
    int jj = f >> 5, ii = f & 31;
    outp[((size_t)b * DK + jj) * LQ + i0 + ii] = tr[jj][ii];
  }
}

// ---------------------------------------------------------------------------
// Kernel 2: direct circular correlation (partial over t)
// corrP[part][row][tau] = sum_{t in part} k[t] * q[t+tau mod L]
// grid (4, 256), block 256; each thread: 16 consecutive tau, sliding window.
// q row staged in LDS with XOR group-swizzle (bank-conflict-free b128 reads).
// ---------------------------------------------------------------------------
__device__ __forceinline__ int swz_g(int g) { return g ^ ((g >> 3) & 7); }

__global__ void corr_kernel(const float* __restrict__ qpT,
                            const float* __restrict__ kpT,
                            float* __restrict__ corrP) {
  const int part = blockIdx.x;   // 0..3
  const int row = blockIdx.y;    // 0..255
  const int tid = threadIdx.x;

  __shared__ __align__(16) float qs[5184];
  __shared__ __align__(16) float ks[1024];

  const float* qr = qpT + (size_t)row * LQ;
  const float* kr = kpT + (size_t)row * LQ;
  const int t0 = part * 1024;

  for (int x = tid; x < 5184; x += 256) {
    int g = x >> 2;
    qs[(swz_g(g) << 2) | (x & 3)] = qr[(t0 + x) & (LQ - 1)];
  }
  for (int x = tid; x < 1024; x += 256) ks[x] = kr[t0 + x];
  __syncthreads();

  const int tau0 = tid * 16;
  float acc[16];
#pragma unroll
  for (int j = 0; j < 16; ++j) acc[j] = 0.f;

  for (int tt = 0; tt < 1024; tt += 16) {
    float kt[16];
#pragma unroll
    for (int i4 = 0; i4 < 16; i4 += 4) {
      float4 kv = *reinterpret_cast<const float4*>(&ks[tt + i4]);
      kt[i4] = kv.x; kt[i4 + 1] = kv.y; kt[i4 + 2] = kv.z; kt[i4 + 3] = kv.w;
    }
    float qw[32];
    const int f0 = tt + tau0;
#pragma unroll
    for (int u = 0; u < 32; u += 4) {
      int g = (f0 + u) >> 2;
      float4 qv = *reinterpret_cast<const float4*>(&qs[swz_g(g) << 2]);
      qw[u] = qv.x; qw[u + 1] = qv.y; qw[u + 2] = qv.z; qw[u + 3] = qv.w;
    }
#pragma unroll
    for (int i = 0; i < 16; ++i)
#pragma unroll
      for (int j = 0; j < 16; ++j)
        acc[j] = fmaf(kt[i], qw[i + j], acc[j]);
  }

  float* cp = corrP + ((size_t)part * NROWS + row) * LQ + tau0;
#pragma unroll
  for (int j4 = 0; j4 < 16; j4 += 4) {
    float4 o; o.x = acc[j4]; o.y = acc[j4 + 1]; o.z = acc[j4 + 2]; o.w = acc[j4 + 3];
    *reinterpret_cast<float4*>(&cp[j4]) = o;
  }
}

// ---------------------------------------------------------------------------
// Kernel 3: top-16 (jax tie-break: smaller index on equal) + softmax
// grid 256, block 256.
// ---------------------------------------------------------------------------
__global__ void topk_kernel(const float* __restrict__ corrP,
                            int* __restrict__ lagB,
                            float* __restrict__ wtB) {
  const int row = blockIdx.x, tid = threadIdx.x;
  const float* c0 = corrP + (size_t)row * LQ;
  const size_t PS = (size_t)NROWS * LQ;

  float v[16]; int ix[16];
#pragma unroll
  for (int m = 0; m < 16; ++m) {
    int tau = m * 256 + tid;
    float s = c0[tau] + c0[PS + tau] + c0[2 * PS + tau] + c0[3 * PS + tau];
    v[m] = fabsf(s);
    ix[m] = tau;
  }

  __shared__ float rv[4]; __shared__ int ri[4];
  __shared__ float sval[TOPK]; __shared__ int sidx[TOPK];
  const int lane = tid & 63, wid = tid >> 6;

  for (int round = 0; round < TOPK; ++round) {
    float bv = -1.f; int bi = 0x7fffffff;
#pragma unroll
    for (int m = 0; m < 16; ++m)
      if (v[m] > bv || (v[m] == bv && ix[m] < bi)) { bv = v[m]; bi = ix[m]; }
#pragma unroll
    for (int off = 32; off > 0; off >>= 1) {
      float ov = __shfl_down(bv, off);
      int oi = __shfl_down(bi, off);
      if (ov > bv || (ov == bv && oi < bi)) { bv = ov; bi = oi; }
    }
    if (lane == 0) { rv[wid] = bv; ri[wid] = bi; }
    __syncthreads();
    if (tid == 0) {
      float fv = rv[0]; int fi = ri[0];
      for (int w = 1; w < 4; ++w)
        if (rv[w] > fv || (rv[w] == fv && ri[w] < fi)) { fv = rv[w]; fi = ri[w]; }
      sval[round] = fv; sidx[round] = fi;
    }
    __syncthreads();
    int widx = sidx[round];
#pragma unroll
    for (int m = 0; m < 16; ++m)
      if (ix[m] == widx) v[m] = -1.f;
  }

  if (tid == 0) {
    float m0 = sval[0], s = 0.f, e[TOPK];
    for (int k = 0; k < TOPK; ++k) { e[k] = expf(sval[k] - m0); s += e[k]; }
    float inv = 1.f / s;
    for (int k = 0; k < TOPK; ++k) {
      wtB[row * TOPK + k] = e[k] * inv;
      lagB[row * TOPK + k] = sidx[k];
    }
  }
}

// ---------------------------------------------------------------------------
// Kernel 4: aggregation  aggT[row][t] = sum_k w_k * v[row][(t+lag_k)%L]
// grid 256, block 256.
// ---------------------------------------------------------------------------
__global__ void agg_kernel(const float* __restrict__ vpT,
                           const int* __restrict__ lagB,
                           const float* __restrict__ wtB,
                           float* __restrict__ aggT) {
  const int row = blockIdx.x, tid = threadIdx.x;
  __shared__ __align__(16) float vr[2 * LQ];
  __shared__ float w[TOPK]; __shared__ int lg[TOPK];

  const float* v0 = vpT + (size_t)row * LQ;
  for (int x = tid; x < LQ; x += 256) {
    float val = v0[x];
    vr[x] = val; vr[x + LQ] = val;
  }
  if (tid < TOPK) { w[tid] = wtB[row * TOPK + tid]; lg[tid] = lagB[row * TOPK + tid]; }
  __syncthreads();

  float wr[TOPK]; int lr[TOPK];
#pragma unroll
  for (int k = 0; k < TOPK; ++k) { wr[k] = w[k]; lr[k] = lg[k]; }

  for (int m = 0; m < 16; ++m) {
    int t = m * 256 + tid;
    float a = 0.f;
#pragma unroll
    for (int k = 0; k < TOPK; ++k) a = fmaf(wr[k], vr[t + lr[k]], a);
    aggT[(size_t)row * LQ + t] = a;
  }
}

// ---------------------------------------------------------------------------
// Kernel 5: transpose + head-broadcast  out[b][t][c] = aggT[b][c&63][t]
// grid (64, 4), block 256.
// ---------------------------------------------------------------------------
__global__ void trans_kernel(const float* __restrict__ aggT,
                             float* __restrict__ out) {
  const int b = blockIdx.y;
  const int t0 = blockIdx.x * 64;
  const int tid = threadIdx.x;
  __shared__ float ts[64][65];

#pragma unroll
  for (int v = 0; v < 16; ++v) {
    int f = v * 256 + tid;        // d = f>>6, tt = f&63
    int d = f >> 6, tt = f & 63;
    ts[d][tt] = aggT[((size_t)b * DK + d) * LQ + t0 + tt];
  }
  __syncthreads();

#pragma unroll
  for (int v = 0; v < 128; ++v) {
    int f = v * 256 + tid;        // tt = f>>9, c = f&511
    int tt = f >> 9, c = f & 511;
    out[((size_t)b * LQ + t0 + tt) * (8 * DK) + c] = ts[c & 63][tt];
  }
}

// ---------------------------------------------------------------------------
extern "C" void kernel_launch(void* const* d_in, const int* in_sizes, int n_in,
                              void* d_out, int out_size, void* d_ws, size_t ws_size,
                              hipStream_t stream) {
  const float* q_in = (const float*)d_in[0];
  const float* k_in = (const float*)d_in[1];
  const float* v_in = (const float*)d_in[2];
  const float* Wq   = (const float*)d_in[3];
  const float* bq   = (const float*)d_in[4];
  float* out = (float*)d_out;
  float* ws  = (float*)d_ws;

  const size_t M = (size_t)BQ * DK * LQ;      // 1,048,576 floats
  float* qpT   = ws;                          // [0, M)
  float* kpT   = ws + M;                      // [M, 2M)
  float* vpT   = ws + 2 * M;                  // [2M, 3M)
  float* corrP = ws + 3 * M;                  // [3M, 7M) : 4 partial buffers
  float* aggT  = ws;                          // reuse qpT (dead after corr)
  int*   lagB  = (int*)(ws + M);              // reuse kpT (dead after corr)
  float* wtB   = ws + M + NROWS * TOPK;

  proj_kernel<<<dim3(512, 1, 3), 256, 0, stream>>>(q_in, k_in, v_in, Wq, bq, ws);
  corr_kernel<<<dim3(4, NROWS), 256, 0, stream>>>(qpT, kpT, corrP);
  topk_kernel<<<NROWS, 256, 0, stream>>>(corrP, lagB, wtB);
  agg_kernel<<<NROWS, 256, 0, stream>>>(vpT, lagB, wtB, aggT);
  trans_kernel<<<dim3(LQ / 64, BQ), 256, 0, stream>>>(aggT, out);
}

// Round 2
// 241.702 us; speedup vs baseline: 2.1936x; 2.1936x over previous
//
#include <hip/hip_runtime.h>
#include <hip/hip_bf16.h>

#define BQ 4
#define LQ 4096
#define DM 512
#define DK 64
#define NROWS (BQ * DK)        // 256
#define TOPK 16

// async global->LDS, 16B per lane; LDS dest must be wave-uniform base.
__device__ __forceinline__ void gl_lds16(const float* g, float* s) {
  auto g1 = (const __attribute__((address_space(1))) float*)(uintptr_t)g;
  auto s3 = (__attribute__((address_space(3))) float*)(uint32_t)(uintptr_t)s;
  __builtin_amdgcn_global_load_lds(g1, s3, 16, 0, 0);
}

// ---------------------------------------------------------------------------
// Kernel 1 v2: projection pT[b][j][i] = sum_k x[b][i][k]*Wq[k][j] + bq[j]
// grid (256, 1, 3), block 256. Block tile 64 rows x 64 cols, BK=64.
// Thread tile 4x4 (ty=tid>>4 row group, tx=tid&15 col group).
// LDS XOR-swizzle: phys quad = (k>>2) ^ ((row>>2)&7)  -> conflict-free reads.
// ---------------------------------------------------------------------------
__global__ __launch_bounds__(256) void proj_kernel(
    const float* __restrict__ q_in, const float* __restrict__ k_in,
    const float* __restrict__ v_in, const float* __restrict__ Wq,
    const float* __restrict__ bq, float* __restrict__ ws) {
  const float* x = blockIdx.z == 0 ? q_in : (blockIdx.z == 1 ? k_in : v_in);
  float* outp = ws + (size_t)blockIdx.z * (size_t)(NROWS * LQ);

  __shared__ __align__(16) float smem[8192];   // 32 KB: xs[4096] | wl[4096]
  float* xs = smem;
  float* wl = smem + 4096;

  const int tid = threadIdx.x;
  const int lane = tid & 63, wvi = tid >> 6;
  const int tx = tid & 15, ty = tid >> 4;
  const int R0 = blockIdx.x * 64;

  float acc[4][4];
#pragma unroll
  for (int r = 0; r < 4; ++r)
#pragma unroll
    for (int c = 0; c < 4; ++c) acc[r][c] = 0.f;

  const int qg = lane & 15, r4 = lane >> 4;
  const int jw = tid & 63, kw = tid >> 6;

  for (int kc = 0; kc < DM; kc += 64) {
    // xs: wave wvi stages rows [wvi*16, wvi*16+16), 4 issues of 4 rows.
#pragma unroll
    for (int is = 0; is < 4; ++is) {
      int row = wvi * 16 + is * 4 + r4;
      int skk = (qg ^ ((row >> 2) & 7)) << 2;   // pre-swizzled source
      gl_lds16(&x[(size_t)(R0 + row) * DM + kc + skk],
               &xs[(wvi * 16 + is * 4) * 64]);
    }
    // wl: transpose W into [j][k] with swizzle, register path.
#pragma unroll
    for (int p = 0; p < 16; ++p) {
      int kk = p * 4 + kw;
      float w = Wq[(size_t)(kc + kk) * DK + jw];
      int phys = (((kk >> 2) ^ ((jw >> 2) & 7)) << 2) | (kk & 3);
      wl[jw * 64 + phys] = w;
    }
    __syncthreads();
#pragma unroll
    for (int kq = 0; kq < 16; ++kq) {
      float4 xv[4], wv[4];
#pragma unroll
      for (int rr = 0; rr < 4; ++rr)
        xv[rr] = *reinterpret_cast<const float4*>(
            &xs[(ty * 4 + rr) * 64 + ((kq ^ (ty & 7)) << 2)]);
#pragma unroll
      for (int cc = 0; cc < 4; ++cc)
        wv[cc] = *reinterpret_cast<const float4*>(
            &wl[(tx * 4 + cc) * 64 + ((kq ^ (tx & 7)) << 2)]);
#pragma unroll
      for (int rr = 0; rr < 4; ++rr)
#pragma unroll
        for (int cc = 0; cc < 4; ++cc) {
          acc[rr][cc] = fmaf(xv[rr].x, wv[cc].x, acc[rr][cc]);
          acc[rr][cc] = fmaf(xv[rr].y, wv[cc].y, acc[rr][cc]);
          acc[rr][cc] = fmaf(xv[rr].z, wv[cc].z, acc[rr][cc]);
          acc[rr][cc] = fmaf(xv[rr].w, wv[cc].w, acc[rr][cc]);
        }
    }
    __syncthreads();
  }

  // epilogue: bias + transpose through LDS (reuse smem), coalesced store.
  float* tr = smem;  // [64][65]
  float bb[4];
#pragma unroll
  for (int cc = 0; cc < 4; ++cc) bb[cc] = bq[tx * 4 + cc];
#pragma unroll
  for (int rr = 0; rr < 4; ++rr)
#pragma unroll
    for (int cc = 0; cc < 4; ++cc)
      tr[(tx * 4 + cc) * 65 + ty * 4 + rr] = acc[rr][cc] + bb[cc];
  __syncthreads();
  const int b = R0 >> 12, i0 = R0 & (LQ - 1);
#pragma unroll
  for (int v = 0; v < 16; ++v) {
    int f = v * 256 + tid;
    int j = f >> 6, i = f & 63;
    outp[((size_t)b * DK + j) * LQ + i0 + i] = tr[j * 65 + i];
  }
}

// ---------------------------------------------------------------------------
// Kernel 2: direct circular correlation (partial over t)
// corrP[part][row][tau] = sum_{t in part} k[t] * q[t+tau mod L]
// ---------------------------------------------------------------------------
__device__ __forceinline__ int swz_g(int g) { return g ^ ((g >> 3) & 7); }

__global__ void corr_kernel(const float* __restrict__ qpT,
                            const float* __restrict__ kpT,
                            float* __restrict__ corrP) {
  const int part = blockIdx.x;   // 0..3
  const int row = blockIdx.y;    // 0..255
  const int tid = threadIdx.x;

  __shared__ __align__(16) float qs[5184];
  __shared__ __align__(16) float ks[1024];

  const float* qr = qpT + (size_t)row * LQ;
  const float* kr = kpT + (size_t)row * LQ;
  const int t0 = part * 1024;

  for (int x = tid; x < 5184; x += 256) {
    int g = x >> 2;
    qs[(swz_g(g) << 2) | (x & 3)] = qr[(t0 + x) & (LQ - 1)];
  }
  for (int x = tid; x < 1024; x += 256) ks[x] = kr[t0 + x];
  __syncthreads();

  const int tau0 = tid * 16;
  float acc[16];
#pragma unroll
  for (int j = 0; j < 16; ++j) acc[j] = 0.f;

  for (int tt = 0; tt < 1024; tt += 16) {
    float kt[16];
#pragma unroll
    for (int i4 = 0; i4 < 16; i4 += 4) {
      float4 kv = *reinterpret_cast<const float4*>(&ks[tt + i4]);
      kt[i4] = kv.x; kt[i4 + 1] = kv.y; kt[i4 + 2] = kv.z; kt[i4 + 3] = kv.w;
    }
    float qw[32];
    const int f0 = tt + tau0;
#pragma unroll
    for (int u = 0; u < 32; u += 4) {
      int g = (f0 + u) >> 2;
      float4 qv = *reinterpret_cast<const float4*>(&qs[swz_g(g) << 2]);
      qw[u] = qv.x; qw[u + 1] = qv.y; qw[u + 2] = qv.z; qw[u + 3] = qv.w;
    }
#pragma unroll
    for (int i = 0; i < 16; ++i)
#pragma unroll
      for (int j = 0; j < 16; ++j)
        acc[j] = fmaf(kt[i], qw[i + j], acc[j]);
  }

  float* cp = corrP + ((size_t)part * NROWS + row) * LQ + tau0;
#pragma unroll
  for (int j4 = 0; j4 < 16; j4 += 4) {
    float4 o; o.x = acc[j4]; o.y = acc[j4 + 1]; o.z = acc[j4 + 2]; o.w = acc[j4 + 3];
    *reinterpret_cast<float4*>(&cp[j4]) = o;
  }
}

// ---------------------------------------------------------------------------
// Kernel 3: top-16 (jax tie-break: smaller index on equal) + softmax
// ---------------------------------------------------------------------------
__global__ void topk_kernel(const float* __restrict__ corrP,
                            int* __restrict__ lagB,
                            float* __restrict__ wtB) {
  const int row = blockIdx.x, tid = threadIdx.x;
  const float* c0 = corrP + (size_t)row * LQ;
  const size_t PS = (size_t)NROWS * LQ;

  float v[16]; int ix[16];
#pragma unroll
  for (int m = 0; m < 16; ++m) {
    int tau = m * 256 + tid;
    float s = c0[tau] + c0[PS + tau] + c0[2 * PS + tau] + c0[3 * PS + tau];
    v[m] = fabsf(s);
    ix[m] = tau;
  }

  __shared__ float rv[4]; __shared__ int ri[4];
  __shared__ float sval[TOPK]; __shared__ int sidx[TOPK];
  const int lane = tid & 63, wid = tid >> 6;

  for (int round = 0; round < TOPK; ++round) {
    float bv = -1.f; int bi = 0x7fffffff;
#pragma unroll
    for (int m = 0; m < 16; ++m)
      if (v[m] > bv || (v[m] == bv && ix[m] < bi)) { bv = v[m]; bi = ix[m]; }
#pragma unroll
    for (int off = 32; off > 0; off >>= 1) {
      float ov = __shfl_down(bv, off);
      int oi = __shfl_down(bi, off);
      if (ov > bv || (ov == bv && oi < bi)) { bv = ov; bi = oi; }
    }
    if (lane == 0) { rv[wid] = bv; ri[wid] = bi; }
    __syncthreads();
    if (tid == 0) {
      float fv = rv[0]; int fi = ri[0];
      for (int w = 1; w < 4; ++w)
        if (rv[w] > fv || (rv[w] == fv && ri[w] < fi)) { fv = rv[w]; fi = ri[w]; }
      sval[round] = fv; sidx[round] = fi;
    }
    __syncthreads();
    int widx = sidx[round];
#pragma unroll
    for (int m = 0; m < 16; ++m)
      if (ix[m] == widx) v[m] = -1.f;
  }

  if (tid == 0) {
    float m0 = sval[0], s = 0.f, e[TOPK];
    for (int k = 0; k < TOPK; ++k) { e[k] = expf(sval[k] - m0); s += e[k]; }
    float inv = 1.f / s;
    for (int k = 0; k < TOPK; ++k) {
      wtB[row * TOPK + k] = e[k] * inv;
      lagB[row * TOPK + k] = sidx[k];
    }
  }
}

// ---------------------------------------------------------------------------
// Kernel 4: aggregation  aggT[row][t] = sum_k w_k * v[row][(t+lag_k)%L]
// ---------------------------------------------------------------------------
__global__ void agg_kernel(const float* __restrict__ vpT,
                           const int* __restrict__ lagB,
                           const float* __restrict__ wtB,
                           float* __restrict__ aggT) {
  const int row = blockIdx.x, tid = threadIdx.x;
  __shared__ __align__(16) float vr[2 * LQ];
  __shared__ float w[TOPK]; __shared__ int lg[TOPK];

  const float* v0 = vpT + (size_t)row * LQ;
  for (int x = tid; x < LQ; x += 256) {
    float val = v0[x];
    vr[x] = val; vr[x + LQ] = val;
  }
  if (tid < TOPK) { w[tid] = wtB[row * TOPK + tid]; lg[tid] = lagB[row * TOPK + tid]; }
  __syncthreads();

  float wr[TOPK]; int lr[TOPK];
#pragma unroll
  for (int k = 0; k < TOPK; ++k) { wr[k] = w[k]; lr[k] = lg[k]; }

  for (int m = 0; m < 16; ++m) {
    int t = m * 256 + tid;
    float a = 0.f;
#pragma unroll
    for (int k = 0; k < TOPK; ++k) a = fmaf(wr[k], vr[t + lr[k]], a);
    aggT[(size_t)row * LQ + t] = a;
  }
}

// ---------------------------------------------------------------------------
// Kernel 5: transpose + head-broadcast  out[b][t][c] = aggT[b][c&63][t]
// ---------------------------------------------------------------------------
__global__ void trans_kernel(const float* __restrict__ aggT,
                             float* __restrict__ out) {
  const int b = blockIdx.y;
  const int t0 = blockIdx.x * 64;
  const int tid = threadIdx.x;
  __shared__ float ts[64][65];

#pragma unroll
  for (int v = 0; v < 16; ++v) {
    int f = v * 256 + tid;
    int d = f >> 6, tt = f & 63;
    ts[d][tt] = aggT[((size_t)b * DK + d) * LQ + t0 + tt];
  }
  __syncthreads();

#pragma unroll
  for (int v = 0; v < 128; ++v) {
    int f = v * 256 + tid;
    int tt = f >> 9, c = f & 511;
    out[((size_t)b * LQ + t0 + tt) * (8 * DK) + c] = ts[c & 63][tt];
  }
}

// ---------------------------------------------------------------------------
extern "C" void kernel_launch(void* const* d_in, const int* in_sizes, int n_in,
                              void* d_out, int out_size, void* d_ws, size_t ws_size,
                              hipStream_t stream) {
  const float* q_in = (const float*)d_in[0];
  const float* k_in = (const float*)d_in[1];
  const float* v_in = (const float*)d_in[2];
  const float* Wq   = (const float*)d_in[3];
  const float* bq   = (const float*)d_in[4];
  float* out = (float*)d_out;
  float* ws  = (float*)d_ws;

  const size_t M = (size_t)BQ * DK * LQ;      // 1,048,576 floats
  float* qpT   = ws;
  float* kpT   = ws + M;
  float* vpT   = ws + 2 * M;
  float* corrP = ws + 3 * M;                  // 4 partial buffers
  float* aggT  = ws;                          // reuse qpT (dead after corr)
  int*   lagB  = (int*)(ws + M);              // reuse kpT (dead after corr)
  float* wtB   = ws + M + NROWS * TOPK;

  proj_kernel<<<dim3(256, 1, 3), 256, 0, stream>>>(q_in, k_in, v_in, Wq, bq, ws);
  corr_kernel<<<dim3(4, NROWS), 256, 0, stream>>>(qpT, kpT, corrP);
  topk_kernel<<<NROWS, 256, 0, stream>>>(corrP, lagB, wtB);
  agg_kernel<<<NROWS, 256, 0, stream>>>(vpT, lagB, wtB, aggT);
  trans_kernel<<<dim3(LQ / 64, BQ), 256, 0, stream>>>(aggT, out);
}